// Round 3
// baseline (344.970 us; speedup 1.0000x reference)
//
#include <hip/hip_runtime.h>
#include <stdint.h>

// RWKV TimeMixing on gfx950. I/O dtype: float32 (per reference).
// Internal: bf16 for MFMA GEMMs + k/v/rsig storage, f32 for WKV scan state.
// R7: (a) GEMM: dropped per-phase lgkmcnt(0) full-drain (compiler-visible
// ds_reads get fine-grained waits); front-loaded A-fragment reads one phase
// ahead so the LDS pipe drains backlog under MFMA windows. (b) scans: pass1/
// pass3 vectorized 4 channels/thread (uint2 loads, G13), NC=64/L=32, state
// arrays (2 MiB each) overlaid on dead bufK region.
// Launches: prep, gemmKV(z=2), gemmR, pass1, pass2, pass3, gemmO (7 total).
// Workspace layout (176 MiB):
//   [0,32M)     bufK bf16 (mix_k); after gemmKV: scan state (6 x 2 MiB)
//   [32M,64M)   bufV bf16 (mix_v); rsig written here after gemmKV
//   [64M,96M)   bufR bf16 (mix_r); rwkv written here after gemmR
//   [96M,128M)  kb bf16
//   [128M,136M) wk/wv/wr/wo bf16 (2 MiB each)
//   [142M,174M) vb bf16

using bf16x8 = __attribute__((ext_vector_type(8))) __bf16;
using f32x4  = __attribute__((ext_vector_type(4))) float;

union FU { float f; unsigned int u; };

__device__ __forceinline__ unsigned short f2b(float f) {
  FU v; v.f = f;
  unsigned int u = v.u;
  return (unsigned short)((u + 0x7fffu + ((u >> 16) & 1u)) >> 16);
}
__device__ __forceinline__ float b2f(unsigned short h) {
  FU v; v.u = ((unsigned int)h) << 16; return v.f;
}

__device__ __forceinline__ void gl_lds16(const unsigned short* g,
                                         const unsigned short* l) {
  __builtin_amdgcn_global_load_lds(
      (const __attribute__((address_space(1))) void*)g,
      (__attribute__((address_space(3))) void*)l, 16, 0, 0);
}

#define SBAR()  asm volatile("s_barrier" ::: "memory")
#define VMW(n)  asm volatile("s_waitcnt vmcnt(" #n ")" ::: "memory")

// ---------------- prep: wconv (blocks 0..4095) + mix3 (blocks 4096..12287) --
__global__ __launch_bounds__(256) void prep_kernel(
    const float* __restrict__ x,
    const float* __restrict__ w0, const float* __restrict__ w1,
    const float* __restrict__ w2, const float* __restrict__ w3,
    unsigned short* __restrict__ o0, unsigned short* __restrict__ o1,
    unsigned short* __restrict__ o2, unsigned short* __restrict__ o3,
    const float* __restrict__ mk, const float* __restrict__ mv,
    const float* __restrict__ mr,
    unsigned short* __restrict__ ok, unsigned short* __restrict__ ov,
    unsigned short* __restrict__ orr, int T, int C)
{
  int bid = blockIdx.x;
  if (bid < 4096) {
    int mat = bid >> 10, blk = bid & 1023;
    const float* src = (mat == 0) ? w0 : (mat == 1) ? w1 : (mat == 2) ? w2 : w3;
    unsigned short* dst = (mat == 0) ? o0 : (mat == 1) ? o1 : (mat == 2) ? o2 : o3;
    int i = blk * 1024 + threadIdx.x * 4;
    float4 v = *(const float4*)(src + i);
    union { int2 i2; unsigned short u[4]; } o;
    o.u[0] = f2b(v.x); o.u[1] = f2b(v.y); o.u[2] = f2b(v.z); o.u[3] = f2b(v.w);
    *(int2*)(dst + i) = o.i2;
    return;
  }
  int i = (bid - 4096) * 256 + threadIdx.x;
  int base = i * 8;
  int row = base / C;          // b*T + t
  int t = row - (row / T) * T; // t within batch
  int c = base - row * C;
  float xv[8], pv[8];
  *(float4*)&xv[0] = *(const float4*)(x + base);
  *(float4*)&xv[4] = *(const float4*)(x + base + 4);
  if (t > 0) {
    *(float4*)&pv[0] = *(const float4*)(x + base - C);
    *(float4*)&pv[4] = *(const float4*)(x + base - C + 4);
  } else {
#pragma unroll
    for (int e = 0; e < 8; ++e) pv[e] = 0.f;
  }
  float mkv[8], mvv[8], mrv[8];
  *(float4*)&mkv[0] = *(const float4*)(mk + c);
  *(float4*)&mkv[4] = *(const float4*)(mk + c + 4);
  *(float4*)&mvv[0] = *(const float4*)(mv + c);
  *(float4*)&mvv[4] = *(const float4*)(mv + c + 4);
  *(float4*)&mrv[0] = *(const float4*)(mr + c);
  *(float4*)&mrv[4] = *(const float4*)(mr + c + 4);
  union { int4 i4; unsigned short u[8]; } a, b2, d;
#pragma unroll
  for (int e = 0; e < 8; ++e) {
    float xe = xv[e], pe = pv[e];
    a.u[e]  = f2b(xe * mkv[e] + pe * (1.f - mkv[e]));
    b2.u[e] = f2b(xe * mvv[e] + pe * (1.f - mvv[e]));
    d.u[e]  = f2b(xe * mrv[e] + pe * (1.f - mrv[e]));
  }
  *(int4*)(ok + base)  = a.i4;
  *(int4*)(ov + base)  = b2.i4;
  *(int4*)(orr + base) = d.i4;
}

// ---------------- 256x256 BK=64 8-wave pipelined GEMM ----------------
// LDS layout per tile: [256 rows][64 bf16] row-major, 128 B/row, with XOR
// swizzle: physical 16B-slot = logical slot ^ (row & 7). Staged via
// global_load_lds (linear LDS dest) with the inverse permutation applied to
// the per-lane GLOBAL source address.

__device__ __forceinline__ void stageHalf(
    const unsigned short* __restrict__ g,  // matrix base + block-row base
    const unsigned short* l,               // LDS tile base (elements)
    int rh, int kt, int w, int rl, int koffel)
{
#pragma unroll
  for (int c = 0; c < 2; ++c) {
    int rows = rh * 128 + (2 * w + c) * 8;   // 8-row subtile base
    gl_lds16(g + (size_t)(rows + rl) * 1024 + kt * 64 + koffel,
             l + rows * 64);
  }
}

template<int Q>
__device__ __forceinline__ void quadMfma(f32x4 (&acc)[8][4],
    bf16x8 a00, bf16x8 a01, bf16x8 a10, bf16x8 a11, bf16x8 (&b)[4][2])
{
#pragma unroll
  for (int j = 0; j < 4; ++j) {
    acc[2*Q][j]   = __builtin_amdgcn_mfma_f32_16x16x32_bf16(a00, b[j][0], acc[2*Q][j],   0, 0, 0);
    acc[2*Q][j]   = __builtin_amdgcn_mfma_f32_16x16x32_bf16(a01, b[j][1], acc[2*Q][j],   0, 0, 0);
    acc[2*Q+1][j] = __builtin_amdgcn_mfma_f32_16x16x32_bf16(a10, b[j][0], acc[2*Q+1][j], 0, 0, 0);
    acc[2*Q+1][j] = __builtin_amdgcn_mfma_f32_16x16x32_bf16(a11, b[j][1], acc[2*Q+1][j], 0, 0, 0);
  }
}

// One K-tile = 4 MFMA phases, reads front-loaded one phase ahead:
//   W0 (tile top): a-set(p1), b[4][2], a-set(p2); stage A(t+1) h0
//   W1: a-set(p3); stage A(t+1) h1
//   W2: a-set(p4); stage B(t+2) h0   (overwrites bR: b consumed at p1, 2 bar ago)
//   W3: stage B(t+2) h1; after p4 MFMA: vmcnt(4) leaves B(t+2) in flight.
// No explicit lgkmcnt drain: ds_reads are compiler-visible; fine-grained
// waits are emitted before each consuming MFMA.
template<bool ST_A, bool ST_B, int VMN>
__device__ __forceinline__ void ktile(
    const unsigned short* aR, const unsigned short* bR,
    const unsigned short* aW, const unsigned short* bW,
    const unsigned short* Am, const unsigned short* Wn,
    int ktA, int ktB, int w, int wm, int wn, int col, int quad,
    int swzel, int rl, int koffel, f32x4 (&acc)[8][4])
{
  const int ks0 = (quad * 8) ^ swzel;        // k-slice 0 slot (elements)
  const int ks1 = (32 + quad * 8) ^ swzel;   // k-slice 1 slot
  const unsigned short* ar = aR + (wm * 128 + col) * 64;

  // ---- W0: front-load p1 a-set, all b, p2 a-set; stage A h0 ----
  bf16x8 a0[4], a1[4];
  a0[0] = *(const bf16x8*)(ar + 0 * 1024 + ks0);
  a0[1] = *(const bf16x8*)(ar + 0 * 1024 + ks1);
  a0[2] = *(const bf16x8*)(ar + 1 * 1024 + ks0);
  a0[3] = *(const bf16x8*)(ar + 1 * 1024 + ks1);
  bf16x8 b[4][2];
#pragma unroll
  for (int j = 0; j < 4; ++j) {
    const unsigned short* br = bR + (wn * 64 + j * 16 + col) * 64;
    b[j][0] = *(const bf16x8*)(br + ks0);
    b[j][1] = *(const bf16x8*)(br + ks1);
  }
  a1[0] = *(const bf16x8*)(ar + 2 * 1024 + ks0);
  a1[1] = *(const bf16x8*)(ar + 2 * 1024 + ks1);
  a1[2] = *(const bf16x8*)(ar + 3 * 1024 + ks0);
  a1[3] = *(const bf16x8*)(ar + 3 * 1024 + ks1);
  if (ST_A) stageHalf(Am, aW, 0, ktA, w, rl, koffel);
  SBAR();
  __builtin_amdgcn_s_setprio(1);
  quadMfma<0>(acc, a0[0], a0[1], a0[2], a0[3], b);
  __builtin_amdgcn_s_setprio(0);
  SBAR();
  // ---- W1: read p3 a-set; stage A h1 ----
  bf16x8 a2[4];
  a2[0] = *(const bf16x8*)(ar + 4 * 1024 + ks0);
  a2[1] = *(const bf16x8*)(ar + 4 * 1024 + ks1);
  a2[2] = *(const bf16x8*)(ar + 5 * 1024 + ks0);
  a2[3] = *(const bf16x8*)(ar + 5 * 1024 + ks1);
  if (ST_A) stageHalf(Am, aW, 1, ktA, w, rl, koffel);
  SBAR();
  __builtin_amdgcn_s_setprio(1);
  quadMfma<1>(acc, a1[0], a1[1], a1[2], a1[3], b);
  __builtin_amdgcn_s_setprio(0);
  SBAR();
  // ---- W2: read p4 a-set; stage B h0 ----
  bf16x8 a3[4];
  a3[0] = *(const bf16x8*)(ar + 6 * 1024 + ks0);
  a3[1] = *(const bf16x8*)(ar + 6 * 1024 + ks1);
  a3[2] = *(const bf16x8*)(ar + 7 * 1024 + ks0);
  a3[3] = *(const bf16x8*)(ar + 7 * 1024 + ks1);
  if (ST_B) stageHalf(Wn, bW, 0, ktB, w, rl, koffel);
  SBAR();
  __builtin_amdgcn_s_setprio(1);
  quadMfma<2>(acc, a2[0], a2[1], a2[2], a2[3], b);
  __builtin_amdgcn_s_setprio(0);
  SBAR();
  // ---- W3: stage B h1; p4 MFMA; vmcnt checkpoint ----
  if (ST_B) stageHalf(Wn, bW, 1, ktB, w, rl, koffel);
  SBAR();
  __builtin_amdgcn_s_setprio(1);
  quadMfma<3>(acc, a3[0], a3[1], a3[2], a3[3], b);
  __builtin_amdgcn_s_setprio(0);
  if constexpr (VMN == 4) { VMW(4); }
  else if constexpr (VMN == 0) { VMW(0); }
  SBAR();
}

template<typename EPI>
__device__ __forceinline__ void gemm256(
    const unsigned short* __restrict__ A,
    const unsigned short* __restrict__ W,
    EPI epi)
{
  __shared__ __align__(16) unsigned short As[2][256 * 64];
  __shared__ __align__(16) unsigned short Bs[2][256 * 64];
  const int tid  = threadIdx.x;
  const int lane = tid & 63;
  const int w    = tid >> 6;          // wave 0..7
  const int wm   = w >> 2, wn = w & 3;
  const int col  = lane & 15, quad = lane >> 4;
  const int swzel  = (lane & 7) << 3;            // read-side XOR (elements)
  const int rl     = lane >> 3;                  // staging row-in-subtile
  const int koffel = ((lane & 7) ^ rl) << 3;     // pre-swizzled global k-off
  const int mBase = blockIdx.x * 256;
  const int nBase = blockIdx.y * 256;
  const unsigned short* Am = A + (size_t)mBase * 1024;
  const unsigned short* Wn = W + (size_t)nBase * 1024;

  f32x4 acc[8][4];
  const f32x4 z = {0.f, 0.f, 0.f, 0.f};
#pragma unroll
  for (int i = 0; i < 8; ++i)
#pragma unroll
    for (int j = 0; j < 4; ++j) acc[i][j] = z;

  // Prologue: B(0), A(0), B(1) = 12 loads/thread; drain oldest 8 (tile 0).
  stageHalf(Wn, &Bs[0][0], 0, 0, w, rl, koffel);
  stageHalf(Wn, &Bs[0][0], 1, 0, w, rl, koffel);
  stageHalf(Am, &As[0][0], 0, 0, w, rl, koffel);
  stageHalf(Am, &As[0][0], 1, 0, w, rl, koffel);
  stageHalf(Wn, &Bs[1][0], 0, 1, w, rl, koffel);
  stageHalf(Wn, &Bs[1][0], 1, 1, w, rl, koffel);
  VMW(4); SBAR();

#pragma unroll 1
  for (int t = 0; t < 14; t += 2) {
    ktile<true, true, 4>(&As[0][0], &Bs[0][0], &As[1][0], &Bs[0][0],
                         Am, Wn, t + 1, t + 2,
                         w, wm, wn, col, quad, swzel, rl, koffel, acc);
    ktile<true, true, 4>(&As[1][0], &Bs[1][0], &As[0][0], &Bs[1][0],
                         Am, Wn, t + 2, t + 3,
                         w, wm, wn, col, quad, swzel, rl, koffel, acc);
  }
  // t = 14: stage only A(15); drain everything (incl. B(15)) at checkpoint.
  ktile<true, false, 0>(&As[0][0], &Bs[0][0], &As[1][0], &Bs[0][0],
                        Am, Wn, 15, 0,
                        w, wm, wn, col, quad, swzel, rl, koffel, acc);
  // t = 15: pure compute.
  ktile<false, false, -1>(&As[1][0], &Bs[1][0], &As[0][0], &Bs[1][0],
                          Am, Wn, 0, 0,
                          w, wm, wn, col, quad, swzel, rl, koffel, acc);

  const int mB = mBase + wm * 128, nB = nBase + wn * 64;
#pragma unroll
  for (int i = 0; i < 8; ++i)
#pragma unroll
    for (int j = 0; j < 4; ++j)
#pragma unroll
      for (int r = 0; r < 4; ++r)
        epi(mB + i * 16 + quad * 4 + r, nB + j * 16 + col, acc[i][j][r]);
}

// fused K/V projection GEMM: z=0 -> kb, z=1 -> vb
__global__ __launch_bounds__(512, 2) void gemmKV2_kernel(
    const unsigned short* __restrict__ A0, const unsigned short* __restrict__ A1,
    const unsigned short* __restrict__ W0, const unsigned short* __restrict__ W1,
    unsigned short* __restrict__ out0, unsigned short* __restrict__ out1)
{
  const int z = blockIdx.z;
  const unsigned short* A = z ? A1 : A0;
  const unsigned short* W = z ? W1 : W0;
  unsigned short* out = z ? out1 : out0;
  gemm256(A, W, [&](int r, int c, float v) {
    out[(size_t)r * 1024 + c] = f2b(v);
  });
}

// R projection: sigmoid epilogue, bf16 out
__global__ __launch_bounds__(512, 2) void gemmR2_kernel(
    const unsigned short* __restrict__ A, const unsigned short* __restrict__ W,
    unsigned short* __restrict__ out)
{
  gemm256(A, W, [&](int r, int c, float v) {
    out[(size_t)r * 1024 + c] = f2b(1.0f / (1.0f + __expf(-v)));
  });
}

// final GEMM: f32 output
__global__ __launch_bounds__(512, 2) void gemmO2_kernel(
    const unsigned short* __restrict__ A, const unsigned short* __restrict__ W,
    float* __restrict__ out)
{
  gemm256(A, W, [&](int r, int c, float v) {
    out[(size_t)r * 1024 + c] = v;
  });
}

// ---------------- WKV chunked scan (NC=64 chunks of L=32, 4 ch/thread) ------
__device__ __forceinline__ void unpack4(uint2 u, float* f) {
  f[0] = b2f((unsigned short)(u.x & 0xffffu));
  f[1] = b2f((unsigned short)(u.x >> 16));
  f[2] = b2f((unsigned short)(u.y & 0xffffu));
  f[3] = b2f((unsigned short)(u.y >> 16));
}

__global__ __launch_bounds__(256) void wkv_pass1(
    const unsigned short* __restrict__ kb, const unsigned short* __restrict__ vb,
    const float* __restrict__ td,
    float* __restrict__ snum, float* __restrict__ sden, float* __restrict__ smx,
    int T, int C)
{
  int g = blockIdx.x * 256 + threadIdx.x;   // 131072 threads
  int cq = g & 255;            // C/4 quads
  int rest = g >> 8;           // b*64 + ch
  int ch = rest & 63;
  int b  = rest >> 6;
  int c0 = cq * 4;
  float4 td4 = *(const float4*)(td + c0);
  float w[4] = {-__expf(td4.x), -__expf(td4.y), -__expf(td4.z), -__expf(td4.w)};
  float num[4] = {0.f, 0.f, 0.f, 0.f};
  float den[4] = {0.f, 0.f, 0.f, 0.f};
  float mx[4]  = {-1e38f, -1e38f, -1e38f, -1e38f};
  size_t base = ((size_t)b * T + (size_t)ch * 32) * C + c0;
  for (int j0 = 0; j0 < 32; j0 += 8) {
    uint2 kq[8], vq[8];
#pragma unroll
    for (int j = 0; j < 8; ++j) {
      size_t a = base + (size_t)(j0 + j) * C;
      kq[j] = *(const uint2*)(kb + a);
      vq[j] = *(const uint2*)(vb + a);
    }
#pragma unroll
    for (int j = 0; j < 8; ++j) {
      float kf[4], vf[4];
      unpack4(kq[j], kf); unpack4(vq[j], vf);
#pragma unroll
      for (int e = 0; e < 4; ++e) {
        float mw = mx[e] + w[e];
        float ms = fmaxf(mw, kf[e]);
        float s1 = __expf(mw - ms);
        float s2 = __expf(kf[e] - ms);
        num[e] = s1 * num[e] + s2 * vf[e];
        den[e] = s1 * den[e] + s2;
        mx[e] = ms;
      }
    }
  }
  int idx = ch * 8192 + b * 1024 + c0;
  *(float4*)(snum + idx) = make_float4(num[0], num[1], num[2], num[3]);
  *(float4*)(sden + idx) = make_float4(den[0], den[1], den[2], den[3]);
  *(float4*)(smx  + idx) = make_float4(mx[0], mx[1], mx[2], mx[3]);
}

__global__ __launch_bounds__(64) void wkv_pass2(
    const float* __restrict__ snum, const float* __restrict__ sden,
    const float* __restrict__ smx, const float* __restrict__ td,
    float* __restrict__ inum, float* __restrict__ iden, float* __restrict__ imx)
{
  int bc = blockIdx.x * 64 + threadIdx.x;   // 8192 threads
  int c = bc & 1023;
  float Wl = -__expf(td[c]) * 32.0f;
  float num = 0.f, den = 0.f, mx = -1e38f;
#pragma unroll
  for (int ch = 0; ch < 64; ++ch) {
    int idx = ch * 8192 + bc;
    inum[idx] = num; iden[idx] = den; imx[idx] = mx;
    float sn = snum[idx], sd = sden[idx], sm = smx[idx];
    float mi = mx + Wl;
    float mo = fmaxf(mi, sm);
    float e1 = __expf(mi - mo);
    float e2 = __expf(sm - mo);
    num = e1 * num + e2 * sn;
    den = e1 * den + e2 * sd;
    mx = mo;
  }
}

__global__ __launch_bounds__(256) void wkv_pass3(
    const unsigned short* __restrict__ kb, const unsigned short* __restrict__ vb,
    const unsigned short* __restrict__ rsig,
    const float* __restrict__ td, const float* __restrict__ tf,
    const float* __restrict__ inum, const float* __restrict__ iden,
    const float* __restrict__ imx,
    unsigned short* __restrict__ rwkv, int T, int C)
{
  int g = blockIdx.x * 256 + threadIdx.x;   // 131072 threads
  int cq = g & 255;
  int rest = g >> 8;
  int ch = rest & 63;
  int b  = rest >> 6;
  int c0 = cq * 4;
  float4 td4 = *(const float4*)(td + c0);
  float4 tf4 = *(const float4*)(tf + c0);
  float w[4] = {-__expf(td4.x), -__expf(td4.y), -__expf(td4.z), -__expf(td4.w)};
  float u[4] = {tf4.x, tf4.y, tf4.z, tf4.w};
  int idx = ch * 8192 + b * 1024 + c0;
  float4 n4 = *(const float4*)(inum + idx);
  float4 d4 = *(const float4*)(iden + idx);
  float4 m4 = *(const float4*)(imx + idx);
  float num[4] = {n4.x, n4.y, n4.z, n4.w};
  float den[4] = {d4.x, d4.y, d4.z, d4.w};
  float mx[4]  = {m4.x, m4.y, m4.z, m4.w};
  size_t base = ((size_t)b * T + (size_t)ch * 32) * C + c0;
  for (int j0 = 0; j0 < 32; j0 += 8) {
    uint2 kq[8], vq[8], rq[8];
#pragma unroll
    for (int j = 0; j < 8; ++j) {
      size_t a = base + (size_t)(j0 + j) * C;
      kq[j] = *(const uint2*)(kb + a);
      vq[j] = *(const uint2*)(vb + a);
      rq[j] = *(const uint2*)(rsig + a);
    }
#pragma unroll
    for (int j = 0; j < 8; ++j) {
      float kf[4], vf[4], rf[4];
      unpack4(kq[j], kf); unpack4(vq[j], vf); unpack4(rq[j], rf);
      union { uint2 u2; unsigned short s[4]; } o;
#pragma unroll
      for (int e = 0; e < 4; ++e) {
        float ku = kf[e] + u[e];
        float mo = fmaxf(mx[e], ku);
        float e1 = __expf(mx[e] - mo);
        float e2 = __expf(ku - mo);
        float out = (e1 * num[e] + e2 * vf[e]) / (e1 * den[e] + e2);
        o.s[e] = f2b(rf[e] * out);
        float mw = mx[e] + w[e];
        float ms = fmaxf(mw, kf[e]);
        float s1 = __expf(mw - ms);
        float s2 = __expf(kf[e] - ms);
        num[e] = s1 * num[e] + s2 * vf[e];
        den[e] = s1 * den[e] + s2;
        mx[e] = ms;
      }
      *(uint2*)(rwkv + base + (size_t)(j0 + j) * C) = o.u2;
    }
  }
}

extern "C" void kernel_launch(void* const* d_in, const int* in_sizes, int n_in,
                              void* d_out, int out_size, void* d_ws, size_t ws_size,
                              hipStream_t stream)
{
  const float* x  = (const float*)d_in[0];
  const float* wk = (const float*)d_in[1];
  const float* wv = (const float*)d_in[2];
  const float* wr = (const float*)d_in[3];
  const float* wo = (const float*)d_in[4];
  const float* td = (const float*)d_in[5];
  const float* tf = (const float*)d_in[6];
  const float* mk = (const float*)d_in[7];
  const float* mv = (const float*)d_in[8];
  const float* mr = (const float*)d_in[9];

  const int B = 8, T = 2048, C = 1024;
  const int M = B * T;      // 16384
  const size_t MB = 1024 * 1024;

  char* ws = (char*)d_ws;
  unsigned short* bufK = (unsigned short*)(ws);              // 32 MiB
  unsigned short* bufV = (unsigned short*)(ws + 32 * MB);    // 32 MiB
  unsigned short* bufR = (unsigned short*)(ws + 64 * MB);    // 32 MiB
  unsigned short* kb   = (unsigned short*)(ws + 96 * MB);    // 32 MiB
  unsigned short* wkb  = (unsigned short*)(ws + 128 * MB);   // 2 MiB each
  unsigned short* wvb  = (unsigned short*)(ws + 130 * MB);
  unsigned short* wrb  = (unsigned short*)(ws + 132 * MB);
  unsigned short* wob  = (unsigned short*)(ws + 134 * MB);
  unsigned short* vb   = (unsigned short*)(ws + 142 * MB);   // 32 MiB
  // scan state (2 MiB each) overlaid on bufK: bufK is dead after gemmKV,
  // pass1 (its first writer) runs strictly after gemmKV.
  float* snum = (float*)(ws + 0 * MB);
  float* sden = (float*)(ws + 2 * MB);
  float* smx  = (float*)(ws + 4 * MB);
  float* inum = (float*)(ws + 6 * MB);
  float* iden = (float*)(ws + 8 * MB);
  float* imx  = (float*)(ws + 10 * MB);
  // reuse (strictly after producer of the region is fully consumed):
  unsigned short* rsig = bufV;  // written by gemmR; bufV dead after gemmKV
  unsigned short* rwkv = bufR;  // written by pass3; bufR dead after gemmR

  dim3 gKV(M / 256, C / 256, 2);   // 64 x 4 x 2 = 512 blocks (2 clean rounds)
  dim3 gG(M / 256, C / 256);       // 64 x 4 = 256 blocks (1 round)

  prep_kernel<<<12288, 256, 0, stream>>>(x, wk, wv, wr, wo, wkb, wvb, wrb, wob,
                                         mk, mv, mr, bufK, bufV, bufR, T, C);
  gemmKV2_kernel<<<gKV, 512, 0, stream>>>(bufK, bufV, wkb, wvb, kb, vb);
  gemmR2_kernel<<<gG, 512, 0, stream>>>(bufR, wrb, rsig);
  wkv_pass1<<<512, 256, 0, stream>>>(kb, vb, td, snum, sden, smx, T, C);
  wkv_pass2<<<128, 64, 0, stream>>>(snum, sden, smx, td, inum, iden, imx);
  wkv_pass3<<<512, 256, 0, stream>>>(kb, vb, rsig, td, tf, inum, iden, imx,
                                     rwkv, T, C);
  gemmO2_kernel<<<gG, 512, 0, stream>>>(rwkv, wob, (float*)d_out);
}

// Round 4
// 342.997 us; speedup vs baseline: 1.0058x; 1.0058x over previous
//
#include <hip/hip_runtime.h>
#include <stdint.h>

// RWKV TimeMixing on gfx950. I/O dtype: float32 (per reference).
// Internal: bf16 for MFMA GEMMs + k/v/rsig storage, f32 for WKV scan state.
// R8: GEMM sync primitives switched to the verified m201 template forms:
// __builtin_amdgcn_s_barrier() (no "memory" clobber) + BARE s_waitcnt asm.
// R5-R7's clobbered asm pinned all ds_reads/VALU inside phase windows ->
// rigid [LDS drain][MFMA] serialization (measured 5550 cyc/K-tile vs
// template's 3300). Clobber-free forms let the scheduler interleave
// next-phase reads into the MFMA shadow while runtime sync is unchanged.
// Launches: prep, gemmKV(z=2), gemmR, pass1, pass2, pass3, gemmO (7 total).
// Workspace layout (176 MiB):
//   [0,32M)     bufK bf16 (mix_k); after gemmKV: scan state (6 x 2 MiB)
//   [32M,64M)   bufV bf16 (mix_v); rsig written here after gemmKV
//   [64M,96M)   bufR bf16 (mix_r); rwkv written here after gemmR
//   [96M,128M)  kb bf16
//   [128M,136M) wk/wv/wr/wo bf16 (2 MiB each)
//   [142M,174M) vb bf16

using bf16x8 = __attribute__((ext_vector_type(8))) __bf16;
using f32x4  = __attribute__((ext_vector_type(4))) float;

union FU { float f; unsigned int u; };

__device__ __forceinline__ unsigned short f2b(float f) {
  FU v; v.f = f;
  unsigned int u = v.u;
  return (unsigned short)((u + 0x7fffu + ((u >> 16) & 1u)) >> 16);
}
__device__ __forceinline__ float b2f(unsigned short h) {
  FU v; v.u = ((unsigned int)h) << 16; return v.f;
}

__device__ __forceinline__ void gl_lds16(const unsigned short* g,
                                         const unsigned short* l) {
  __builtin_amdgcn_global_load_lds(
      (const __attribute__((address_space(1))) void*)g,
      (__attribute__((address_space(3))) void*)l, 16, 0, 0);
}

// m201 template forms: runtime sync without compiler-visible memory ordering.
#define SBAR()  __builtin_amdgcn_s_barrier()
#define LGKM0() asm volatile("s_waitcnt lgkmcnt(0)")
#define VMW(n)  asm volatile("s_waitcnt vmcnt(" #n ")")

// ---------------- prep: wconv (blocks 0..4095) + mix3 (blocks 4096..12287) --
__global__ __launch_bounds__(256) void prep_kernel(
    const float* __restrict__ x,
    const float* __restrict__ w0, const float* __restrict__ w1,
    const float* __restrict__ w2, const float* __restrict__ w3,
    unsigned short* __restrict__ o0, unsigned short* __restrict__ o1,
    unsigned short* __restrict__ o2, unsigned short* __restrict__ o3,
    const float* __restrict__ mk, const float* __restrict__ mv,
    const float* __restrict__ mr,
    unsigned short* __restrict__ ok, unsigned short* __restrict__ ov,
    unsigned short* __restrict__ orr, int T, int C)
{
  int bid = blockIdx.x;
  if (bid < 4096) {
    int mat = bid >> 10, blk = bid & 1023;
    const float* src = (mat == 0) ? w0 : (mat == 1) ? w1 : (mat == 2) ? w2 : w3;
    unsigned short* dst = (mat == 0) ? o0 : (mat == 1) ? o1 : (mat == 2) ? o2 : o3;
    int i = blk * 1024 + threadIdx.x * 4;
    float4 v = *(const float4*)(src + i);
    union { int2 i2; unsigned short u[4]; } o;
    o.u[0] = f2b(v.x); o.u[1] = f2b(v.y); o.u[2] = f2b(v.z); o.u[3] = f2b(v.w);
    *(int2*)(dst + i) = o.i2;
    return;
  }
  int i = (bid - 4096) * 256 + threadIdx.x;
  int base = i * 8;
  int row = base / C;          // b*T + t
  int t = row - (row / T) * T; // t within batch
  int c = base - row * C;
  float xv[8], pv[8];
  *(float4*)&xv[0] = *(const float4*)(x + base);
  *(float4*)&xv[4] = *(const float4*)(x + base + 4);
  if (t > 0) {
    *(float4*)&pv[0] = *(const float4*)(x + base - C);
    *(float4*)&pv[4] = *(const float4*)(x + base - C + 4);
  } else {
#pragma unroll
    for (int e = 0; e < 8; ++e) pv[e] = 0.f;
  }
  float mkv[8], mvv[8], mrv[8];
  *(float4*)&mkv[0] = *(const float4*)(mk + c);
  *(float4*)&mkv[4] = *(const float4*)(mk + c + 4);
  *(float4*)&mvv[0] = *(const float4*)(mv + c);
  *(float4*)&mvv[4] = *(const float4*)(mv + c + 4);
  *(float4*)&mrv[0] = *(const float4*)(mr + c);
  *(float4*)&mrv[4] = *(const float4*)(mr + c + 4);
  union { int4 i4; unsigned short u[8]; } a, b2, d;
#pragma unroll
  for (int e = 0; e < 8; ++e) {
    float xe = xv[e], pe = pv[e];
    a.u[e]  = f2b(xe * mkv[e] + pe * (1.f - mkv[e]));
    b2.u[e] = f2b(xe * mvv[e] + pe * (1.f - mvv[e]));
    d.u[e]  = f2b(xe * mrv[e] + pe * (1.f - mrv[e]));
  }
  *(int4*)(ok + base)  = a.i4;
  *(int4*)(ov + base)  = b2.i4;
  *(int4*)(orr + base) = d.i4;
}

// ---------------- 256x256 BK=64 8-wave pipelined GEMM ----------------
// LDS layout per tile: [256 rows][64 bf16] row-major, 128 B/row, with XOR
// swizzle: physical 16B-slot = logical slot ^ (row & 7). Staged via
// global_load_lds (linear LDS dest) with the inverse permutation applied to
// the per-lane GLOBAL source address.

__device__ __forceinline__ void stageHalf(
    const unsigned short* __restrict__ g,  // matrix base + block-row base
    const unsigned short* l,               // LDS tile base (elements)
    int rh, int kt, int w, int rl, int koffel)
{
#pragma unroll
  for (int c = 0; c < 2; ++c) {
    int rows = rh * 128 + (2 * w + c) * 8;   // 8-row subtile base
    gl_lds16(g + (size_t)(rows + rl) * 1024 + kt * 64 + koffel,
             l + rows * 64);
  }
}

template<int Q>
__device__ __forceinline__ void quadMfma(f32x4 (&acc)[8][4],
    bf16x8 a00, bf16x8 a01, bf16x8 a10, bf16x8 a11, bf16x8 (&b)[4][2])
{
#pragma unroll
  for (int j = 0; j < 4; ++j) {
    acc[2*Q][j]   = __builtin_amdgcn_mfma_f32_16x16x32_bf16(a00, b[j][0], acc[2*Q][j],   0, 0, 0);
    acc[2*Q][j]   = __builtin_amdgcn_mfma_f32_16x16x32_bf16(a01, b[j][1], acc[2*Q][j],   0, 0, 0);
    acc[2*Q+1][j] = __builtin_amdgcn_mfma_f32_16x16x32_bf16(a10, b[j][0], acc[2*Q+1][j], 0, 0, 0);
    acc[2*Q+1][j] = __builtin_amdgcn_mfma_f32_16x16x32_bf16(a11, b[j][1], acc[2*Q+1][j], 0, 0, 0);
  }
}

// One K-tile = 4 phases. Phase q: quadrant (m-rows 2q,2q+1) x 4n x K=64.
// Stage schedule (overwrite-safe, >=1 barrier between old-content readers
// and the stage issue):
//   p1: A half0 of tile kt+1 -> other buffer
//   p2: A half1 of tile kt+1 -> other buffer
//   p3: B half0 of tile kt+2 -> SAME buffer (b consumed at p1, 2 barriers ago)
//   p4: B half1 of tile kt+2 -> SAME buffer; then vmcnt checkpoint.
// Checkpoint vmcnt(4): leaves exactly the 2 newest half-tiles (B(t+2)) in
// flight; everything tile t+1 needs is drained.
template<bool ST_A, bool ST_B, int VMN>
__device__ __forceinline__ void ktile(
    const unsigned short* aR, const unsigned short* bR,
    const unsigned short* aW, const unsigned short* bW,
    const unsigned short* Am, const unsigned short* Wn,
    int ktA, int ktB, int w, int wm, int wn, int col, int quad,
    int swzel, int rl, int koffel, f32x4 (&acc)[8][4])
{
  const int ks0 = (quad * 8) ^ swzel;        // k-slice 0 slot (elements)
  const int ks1 = (32 + quad * 8) ^ swzel;   // k-slice 1 slot
  // B fragments for the whole tile, kept in registers through all 4 phases
  bf16x8 b[4][2];
#pragma unroll
  for (int j = 0; j < 4; ++j) {
    const unsigned short* br = bR + (wn * 64 + j * 16 + col) * 64;
    b[j][0] = *(const bf16x8*)(br + ks0);
    b[j][1] = *(const bf16x8*)(br + ks1);
  }
  const unsigned short* ar = aR + (wm * 128 + col) * 64;
  // ---- Phase 1 (quadrant 0) ----
  {
    bf16x8 a00 = *(const bf16x8*)(ar + 0 * 1024 + ks0);
    bf16x8 a01 = *(const bf16x8*)(ar + 0 * 1024 + ks1);
    bf16x8 a10 = *(const bf16x8*)(ar + 1 * 1024 + ks0);
    bf16x8 a11 = *(const bf16x8*)(ar + 1 * 1024 + ks1);
    if (ST_A) stageHalf(Am, aW, 0, ktA, w, rl, koffel);
    SBAR(); LGKM0();
    __builtin_amdgcn_s_setprio(1);
    quadMfma<0>(acc, a00, a01, a10, a11, b);
    __builtin_amdgcn_s_setprio(0);
    SBAR();
  }
  // ---- Phase 2 (quadrant 1) ----
  {
    bf16x8 a00 = *(const bf16x8*)(ar + 2 * 1024 + ks0);
    bf16x8 a01 = *(const bf16x8*)(ar + 2 * 1024 + ks1);
    bf16x8 a10 = *(const bf16x8*)(ar + 3 * 1024 + ks0);
    bf16x8 a11 = *(const bf16x8*)(ar + 3 * 1024 + ks1);
    if (ST_A) stageHalf(Am, aW, 1, ktA, w, rl, koffel);
    SBAR(); LGKM0();
    __builtin_amdgcn_s_setprio(1);
    quadMfma<1>(acc, a00, a01, a10, a11, b);
    __builtin_amdgcn_s_setprio(0);
    SBAR();
  }
  // ---- Phase 3 (quadrant 2) ----
  {
    bf16x8 a00 = *(const bf16x8*)(ar + 4 * 1024 + ks0);
    bf16x8 a01 = *(const bf16x8*)(ar + 4 * 1024 + ks1);
    bf16x8 a10 = *(const bf16x8*)(ar + 5 * 1024 + ks0);
    bf16x8 a11 = *(const bf16x8*)(ar + 5 * 1024 + ks1);
    if (ST_B) stageHalf(Wn, bW, 0, ktB, w, rl, koffel);
    SBAR(); LGKM0();
    __builtin_amdgcn_s_setprio(1);
    quadMfma<2>(acc, a00, a01, a10, a11, b);
    __builtin_amdgcn_s_setprio(0);
    SBAR();
  }
  // ---- Phase 4 (quadrant 3) + vmcnt checkpoint ----
  {
    bf16x8 a00 = *(const bf16x8*)(ar + 6 * 1024 + ks0);
    bf16x8 a01 = *(const bf16x8*)(ar + 6 * 1024 + ks1);
    bf16x8 a10 = *(const bf16x8*)(ar + 7 * 1024 + ks0);
    bf16x8 a11 = *(const bf16x8*)(ar + 7 * 1024 + ks1);
    if (ST_B) stageHalf(Wn, bW, 1, ktB, w, rl, koffel);
    SBAR(); LGKM0();
    __builtin_amdgcn_s_setprio(1);
    quadMfma<3>(acc, a00, a01, a10, a11, b);
    __builtin_amdgcn_s_setprio(0);
    if constexpr (VMN == 4) { VMW(4); }
    else if constexpr (VMN == 0) { VMW(0); }
    SBAR();
  }
}

template<typename EPI>
__device__ __forceinline__ void gemm256(
    const unsigned short* __restrict__ A,
    const unsigned short* __restrict__ W,
    EPI epi)
{
  __shared__ __align__(16) unsigned short As[2][256 * 64];
  __shared__ __align__(16) unsigned short Bs[2][256 * 64];
  const int tid  = threadIdx.x;
  const int lane = tid & 63;
  const int w    = tid >> 6;          // wave 0..7
  const int wm   = w >> 2, wn = w & 3;
  const int col  = lane & 15, quad = lane >> 4;
  const int swzel  = (lane & 7) << 3;            // read-side XOR (elements)
  const int rl     = lane >> 3;                  // staging row-in-subtile
  const int koffel = ((lane & 7) ^ rl) << 3;     // pre-swizzled global k-off
  const int mBase = blockIdx.x * 256;
  const int nBase = blockIdx.y * 256;
  const unsigned short* Am = A + (size_t)mBase * 1024;
  const unsigned short* Wn = W + (size_t)nBase * 1024;

  f32x4 acc[8][4];
  const f32x4 z = {0.f, 0.f, 0.f, 0.f};
#pragma unroll
  for (int i = 0; i < 8; ++i)
#pragma unroll
    for (int j = 0; j < 4; ++j) acc[i][j] = z;

  // Prologue: B(0), A(0), B(1) = 12 loads/thread; drain oldest 8 (tile 0).
  stageHalf(Wn, &Bs[0][0], 0, 0, w, rl, koffel);
  stageHalf(Wn, &Bs[0][0], 1, 0, w, rl, koffel);
  stageHalf(Am, &As[0][0], 0, 0, w, rl, koffel);
  stageHalf(Am, &As[0][0], 1, 0, w, rl, koffel);
  stageHalf(Wn, &Bs[1][0], 0, 1, w, rl, koffel);
  stageHalf(Wn, &Bs[1][0], 1, 1, w, rl, koffel);
  VMW(4); SBAR();

#pragma unroll 1
  for (int t = 0; t < 14; t += 2) {
    ktile<true, true, 4>(&As[0][0], &Bs[0][0], &As[1][0], &Bs[0][0],
                         Am, Wn, t + 1, t + 2,
                         w, wm, wn, col, quad, swzel, rl, koffel, acc);
    ktile<true, true, 4>(&As[1][0], &Bs[1][0], &As[0][0], &Bs[1][0],
                         Am, Wn, t + 2, t + 3,
                         w, wm, wn, col, quad, swzel, rl, koffel, acc);
  }
  // t = 14: stage only A(15); drain everything (incl. B(15)) at checkpoint.
  ktile<true, false, 0>(&As[0][0], &Bs[0][0], &As[1][0], &Bs[0][0],
                        Am, Wn, 15, 0,
                        w, wm, wn, col, quad, swzel, rl, koffel, acc);
  // t = 15: pure compute.
  ktile<false, false, -1>(&As[1][0], &Bs[1][0], &As[0][0], &Bs[1][0],
                          Am, Wn, 0, 0,
                          w, wm, wn, col, quad, swzel, rl, koffel, acc);

  const int mB = mBase + wm * 128, nB = nBase + wn * 64;
#pragma unroll
  for (int i = 0; i < 8; ++i)
#pragma unroll
    for (int j = 0; j < 4; ++j)
#pragma unroll
      for (int r = 0; r < 4; ++r)
        epi(mB + i * 16 + quad * 4 + r, nB + j * 16 + col, acc[i][j][r]);
}

// fused K/V projection GEMM: z=0 -> kb, z=1 -> vb
__global__ __launch_bounds__(512, 2) void gemmKV2_kernel(
    const unsigned short* __restrict__ A0, const unsigned short* __restrict__ A1,
    const unsigned short* __restrict__ W0, const unsigned short* __restrict__ W1,
    unsigned short* __restrict__ out0, unsigned short* __restrict__ out1)
{
  const int z = blockIdx.z;
  const unsigned short* A = z ? A1 : A0;
  const unsigned short* W = z ? W1 : W0;
  unsigned short* out = z ? out1 : out0;
  gemm256(A, W, [&](int r, int c, float v) {
    out[(size_t)r * 1024 + c] = f2b(v);
  });
}

// R projection: sigmoid epilogue, bf16 out
__global__ __launch_bounds__(512, 2) void gemmR2_kernel(
    const unsigned short* __restrict__ A, const unsigned short* __restrict__ W,
    unsigned short* __restrict__ out)
{
  gemm256(A, W, [&](int r, int c, float v) {
    out[(size_t)r * 1024 + c] = f2b(1.0f / (1.0f + __expf(-v)));
  });
}

// final GEMM: f32 output
__global__ __launch_bounds__(512, 2) void gemmO2_kernel(
    const unsigned short* __restrict__ A, const unsigned short* __restrict__ W,
    float* __restrict__ out)
{
  gemm256(A, W, [&](int r, int c, float v) {
    out[(size_t)r * 1024 + c] = v;
  });
}

// ---------------- WKV chunked scan (NC=64 chunks of L=32, 4 ch/thread) ------
__device__ __forceinline__ void unpack4(uint2 u, float* f) {
  f[0] = b2f((unsigned short)(u.x & 0xffffu));
  f[1] = b2f((unsigned short)(u.x >> 16));
  f[2] = b2f((unsigned short)(u.y & 0xffffu));
  f[3] = b2f((unsigned short)(u.y >> 16));
}

__global__ __launch_bounds__(256) void wkv_pass1(
    const unsigned short* __restrict__ kb, const unsigned short* __restrict__ vb,
    const float* __restrict__ td,
    float* __restrict__ snum, float* __restrict__ sden, float* __restrict__ smx,
    int T, int C)
{
  int g = blockIdx.x * 256 + threadIdx.x;   // 131072 threads
  int cq = g & 255;            // C/4 quads
  int rest = g >> 8;           // b*64 + ch
  int ch = rest & 63;
  int b  = rest >> 6;
  int c0 = cq * 4;
  float4 td4 = *(const float4*)(td + c0);
  float w[4] = {-__expf(td4.x), -__expf(td4.y), -__expf(td4.z), -__expf(td4.w)};
  float num[4] = {0.f, 0.f, 0.f, 0.f};
  float den[4] = {0.f, 0.f, 0.f, 0.f};
  float mx[4]  = {-1e38f, -1e38f, -1e38f, -1e38f};
  size_t base = ((size_t)b * T + (size_t)ch * 32) * C + c0;
  for (int j0 = 0; j0 < 32; j0 += 8) {
    uint2 kq[8], vq[8];
#pragma unroll
    for (int j = 0; j < 8; ++j) {
      size_t a = base + (size_t)(j0 + j) * C;
      kq[j] = *(const uint2*)(kb + a);
      vq[j] = *(const uint2*)(vb + a);
    }
#pragma unroll
    for (int j = 0; j < 8; ++j) {
      float kf[4], vf[4];
      unpack4(kq[j], kf); unpack4(vq[j], vf);
#pragma unroll
      for (int e = 0; e < 4; ++e) {
        float mw = mx[e] + w[e];
        float ms = fmaxf(mw, kf[e]);
        float s1 = __expf(mw - ms);
        float s2 = __expf(kf[e] - ms);
        num[e] = s1 * num[e] + s2 * vf[e];
        den[e] = s1 * den[e] + s2;
        mx[e] = ms;
      }
    }
  }
  int idx = ch * 8192 + b * 1024 + c0;
  *(float4*)(snum + idx) = make_float4(num[0], num[1], num[2], num[3]);
  *(float4*)(sden + idx) = make_float4(den[0], den[1], den[2], den[3]);
  *(float4*)(smx  + idx) = make_float4(mx[0], mx[1], mx[2], mx[3]);
}

__global__ __launch_bounds__(64) void wkv_pass2(
    const float* __restrict__ snum, const float* __restrict__ sden,
    const float* __restrict__ smx, const float* __restrict__ td,
    float* __restrict__ inum, float* __restrict__ iden, float* __restrict__ imx)
{
  int bc = blockIdx.x * 64 + threadIdx.x;   // 8192 threads
  int c = bc & 1023;
  float Wl = -__expf(td[c]) * 32.0f;
  float num = 0.f, den = 0.f, mx = -1e38f;
#pragma unroll
  for (int ch = 0; ch < 64; ++ch) {
    int idx = ch * 8192 + bc;
    inum[idx] = num; iden[idx] = den; imx[idx] = mx;
    float sn = snum[idx], sd = sden[idx], sm = smx[idx];
    float mi = mx + Wl;
    float mo = fmaxf(mi, sm);
    float e1 = __expf(mi - mo);
    float e2 = __expf(sm - mo);
    num = e1 * num + e2 * sn;
    den = e1 * den + e2 * sd;
    mx = mo;
  }
}

__global__ __launch_bounds__(256) void wkv_pass3(
    const unsigned short* __restrict__ kb, const unsigned short* __restrict__ vb,
    const unsigned short* __restrict__ rsig,
    const float* __restrict__ td, const float* __restrict__ tf,
    const float* __restrict__ inum, const float* __restrict__ iden,
    const float* __restrict__ imx,
    unsigned short* __restrict__ rwkv, int T, int C)
{
  int g = blockIdx.x * 256 + threadIdx.x;   // 131072 threads
  int cq = g & 255;
  int rest = g >> 8;
  int ch = rest & 63;
  int b  = rest >> 6;
  int c0 = cq * 4;
  float4 td4 = *(const float4*)(td + c0);
  float4 tf4 = *(const float4*)(tf + c0);
  float w[4] = {-__expf(td4.x), -__expf(td4.y), -__expf(td4.z), -__expf(td4.w)};
  float u[4] = {tf4.x, tf4.y, tf4.z, tf4.w};
  int idx = ch * 8192 + b * 1024 + c0;
  float4 n4 = *(const float4*)(inum + idx);
  float4 d4 = *(const float4*)(iden + idx);
  float4 m4 = *(const float4*)(imx + idx);
  float num[4] = {n4.x, n4.y, n4.z, n4.w};
  float den[4] = {d4.x, d4.y, d4.z, d4.w};
  float mx[4]  = {m4.x, m4.y, m4.z, m4.w};
  size_t base = ((size_t)b * T + (size_t)ch * 32) * C + c0;
  for (int j0 = 0; j0 < 32; j0 += 8) {
    uint2 kq[8], vq[8], rq[8];
#pragma unroll
    for (int j = 0; j < 8; ++j) {
      size_t a = base + (size_t)(j0 + j) * C;
      kq[j] = *(const uint2*)(kb + a);
      vq[j] = *(const uint2*)(vb + a);
      rq[j] = *(const uint2*)(rsig + a);
    }
#pragma unroll
    for (int j = 0; j < 8; ++j) {
      float kf[4], vf[4], rf[4];
      unpack4(kq[j], kf); unpack4(vq[j], vf); unpack4(rq[j], rf);
      union { uint2 u2; unsigned short s[4]; } o;
#pragma unroll
      for (int e = 0; e < 4; ++e) {
        float ku = kf[e] + u[e];
        float mo = fmaxf(mx[e], ku);
        float e1 = __expf(mx[e] - mo);
        float e2 = __expf(ku - mo);
        float out = (e1 * num[e] + e2 * vf[e]) / (e1 * den[e] + e2);
        o.s[e] = f2b(rf[e] * out);
        float mw = mx[e] + w[e];
        float ms = fmaxf(mw, kf[e]);
        float s1 = __expf(mw - ms);
        float s2 = __expf(kf[e] - ms);
        num[e] = s1 * num[e] + s2 * vf[e];
        den[e] = s1 * den[e] + s2;
        mx[e] = ms;
      }
      *(uint2*)(rwkv + base + (size_t)(j0 + j) * C) = o.u2;
    }
  }
}

extern "C" void kernel_launch(void* const* d_in, const int* in_sizes, int n_in,
                              void* d_out, int out_size, void* d_ws, size_t ws_size,
                              hipStream_t stream)
{
  const float* x  = (const float*)d_in[0];
  const float* wk = (const float*)d_in[1];
  const float* wv = (const float*)d_in[2];
  const float* wr = (const float*)d_in[3];
  const float* wo = (const float*)d_in[4];
  const float* td = (const float*)d_in[5];
  const float* tf = (const float*)d_in[6];
  const float* mk = (const float*)d_in[7];
  const float* mv = (const float*)d_in[8];
  const float* mr = (const float*)d_in[9];

  const int B = 8, T = 2048, C = 1024;
  const int M = B * T;      // 16384
  const size_t MB = 1024 * 1024;

  char* ws = (char*)d_ws;
  unsigned short* bufK = (unsigned short*)(ws);              // 32 MiB
  unsigned short* bufV = (unsigned short*)(ws + 32 * MB);    // 32 MiB
  unsigned short* bufR = (unsigned short*)(ws + 64 * MB);    // 32 MiB
  unsigned short* kb   = (unsigned short*)(ws + 96 * MB);    // 32 MiB
  unsigned short* wkb  = (unsigned short*)(ws + 128 * MB);   // 2 MiB each
  unsigned short* wvb  = (unsigned short*)(ws + 130 * MB);
  unsigned short* wrb  = (unsigned short*)(ws + 132 * MB);
  unsigned short* wob  = (unsigned short*)(ws + 134 * MB);
  unsigned short* vb   = (unsigned short*)(ws + 142 * MB);   // 32 MiB
  // scan state (2 MiB each) overlaid on bufK: bufK is dead after gemmKV,
  // pass1 (its first writer) runs strictly after gemmKV.
  float* snum = (float*)(ws + 0 * MB);
  float* sden = (float*)(ws + 2 * MB);
  float* smx  = (float*)(ws + 4 * MB);
  float* inum = (float*)(ws + 6 * MB);
  float* iden = (float*)(ws + 8 * MB);
  float* imx  = (float*)(ws + 10 * MB);
  // reuse (strictly after producer of the region is fully consumed):
  unsigned short* rsig = bufV;  // written by gemmR; bufV dead after gemmKV
  unsigned short* rwkv = bufR;  // written by pass3; bufR dead after gemmR

  dim3 gKV(M / 256, C / 256, 2);   // 64 x 4 x 2 = 512 blocks (2 clean rounds)
  dim3 gG(M / 256, C / 256);       // 64 x 4 = 256 blocks (1 round)

  prep_kernel<<<12288, 256, 0, stream>>>(x, wk, wv, wr, wo, wkb, wvb, wrb, wob,
                                         mk, mv, mr, bufK, bufV, bufR, T, C);
  gemmKV2_kernel<<<gKV, 512, 0, stream>>>(bufK, bufV, wkb, wvb, kb, vb);
  gemmR2_kernel<<<gG, 512, 0, stream>>>(bufR, wrb, rsig);
  wkv_pass1<<<512, 256, 0, stream>>>(kb, vb, td, snum, sden, smx, T, C);
  wkv_pass2<<<128, 64, 0, stream>>>(snum, sden, smx, td, inum, iden, imx);
  wkv_pass3<<<512, 256, 0, stream>>>(kb, vb, rsig, td, tf, inum, iden, imx,
                                     rwkv, T, C);
  gemmO2_kernel<<<gG, 512, 0, stream>>>(rwkv, wob, (float*)d_out);
}

// Round 6
// 331.768 us; speedup vs baseline: 1.0398x; 1.0338x over previous
//
#include <hip/hip_runtime.h>
#include <stdint.h>

// RWKV TimeMixing on gfx950. I/O dtype: float32 (per reference).
// Internal: bf16 for MFMA GEMMs + k/v/rsig storage, f32 for WKV scan state.
// R10: recovery round. R9's 2-phase GEMM raced (single-barrier separation
// between last-read and overwrite-stage; raw s_barrier is not a compiler
// fence, reads/MFMAs can sink past it). REVERT to R8's 4-phase GEMM
// (2-barrier separation, proven). Scans reverted to R6 form (NC=32/L=64,
// scalar loads) - the R7 NC=64 rework was a measured -10us regression.
// prep: runtime divides replaced with shifts (C=1024, T=2048 constants).
// Launches: prep, gemmKV(z=2), gemmR, pass1, pass2, pass3, gemmO (7 total).
// Workspace layout (176 MiB):
//   [0,32M)     bufK bf16 (mix_k)
//   [32M,64M)   bufV bf16 (mix_v); rsig written here after gemmKV
//   [64M,96M)   bufR bf16 (mix_r); rwkv written here after gemmR
//   [96M,128M)  kb bf16
//   [128M,136M) wk/wv/wr/wo bf16 (2 MiB each)
//   [136M,142M) scan scratch: snum,sden,smx,inum,iden,imx (1 MiB each)
//   [142M,174M) vb bf16

using bf16x8 = __attribute__((ext_vector_type(8))) __bf16;
using f32x4  = __attribute__((ext_vector_type(4))) float;

union FU { float f; unsigned int u; };

__device__ __forceinline__ unsigned short f2b(float f) {
  FU v; v.f = f;
  unsigned int u = v.u;
  return (unsigned short)((u + 0x7fffu + ((u >> 16) & 1u)) >> 16);
}
__device__ __forceinline__ float b2f(unsigned short h) {
  FU v; v.u = ((unsigned int)h) << 16; return v.f;
}

__device__ __forceinline__ void gl_lds16(const unsigned short* g,
                                         const unsigned short* l) {
  __builtin_amdgcn_global_load_lds(
      (const __attribute__((address_space(1))) void*)g,
      (__attribute__((address_space(3))) void*)l, 16, 0, 0);
}

// m201 template forms: runtime sync without compiler-visible memory ordering.
#define SBAR()  __builtin_amdgcn_s_barrier()
#define LGKM0() asm volatile("s_waitcnt lgkmcnt(0)")
#define VMW(n)  asm volatile("s_waitcnt vmcnt(" #n ")")

// ---------------- prep: wconv (blocks 0..4095) + mix3 (blocks 4096..12287) --
__global__ __launch_bounds__(256) void prep_kernel(
    const float* __restrict__ x,
    const float* __restrict__ w0, const float* __restrict__ w1,
    const float* __restrict__ w2, const float* __restrict__ w3,
    unsigned short* __restrict__ o0, unsigned short* __restrict__ o1,
    unsigned short* __restrict__ o2, unsigned short* __restrict__ o3,
    const float* __restrict__ mk, const float* __restrict__ mv,
    const float* __restrict__ mr,
    unsigned short* __restrict__ ok, unsigned short* __restrict__ ov,
    unsigned short* __restrict__ orr)
{
  int bid = blockIdx.x;
  if (bid < 4096) {
    int mat = bid >> 10, blk = bid & 1023;
    const float* src = (mat == 0) ? w0 : (mat == 1) ? w1 : (mat == 2) ? w2 : w3;
    unsigned short* dst = (mat == 0) ? o0 : (mat == 1) ? o1 : (mat == 2) ? o2 : o3;
    int i = blk * 1024 + threadIdx.x * 4;
    float4 v = *(const float4*)(src + i);
    union { int2 i2; unsigned short u[4]; } o;
    o.u[0] = f2b(v.x); o.u[1] = f2b(v.y); o.u[2] = f2b(v.z); o.u[3] = f2b(v.w);
    *(int2*)(dst + i) = o.i2;
    return;
  }
  int i = (bid - 4096) * 256 + threadIdx.x;
  int base = i * 8;             // C=1024, T=2048 compile-time facts
  int row = base >> 10;         // b*T + t
  int t = row & 2047;           // t within batch
  int c = base & 1023;
  float xv[8], pv[8];
  *(float4*)&xv[0] = *(const float4*)(x + base);
  *(float4*)&xv[4] = *(const float4*)(x + base + 4);
  if (t > 0) {
    *(float4*)&pv[0] = *(const float4*)(x + base - 1024);
    *(float4*)&pv[4] = *(const float4*)(x + base - 1024 + 4);
  } else {
#pragma unroll
    for (int e = 0; e < 8; ++e) pv[e] = 0.f;
  }
  float mkv[8], mvv[8], mrv[8];
  *(float4*)&mkv[0] = *(const float4*)(mk + c);
  *(float4*)&mkv[4] = *(const float4*)(mk + c + 4);
  *(float4*)&mvv[0] = *(const float4*)(mv + c);
  *(float4*)&mvv[4] = *(const float4*)(mv + c + 4);
  *(float4*)&mrv[0] = *(const float4*)(mr + c);
  *(float4*)&mrv[4] = *(const float4*)(mr + c + 4);
  union { int4 i4; unsigned short u[8]; } a, b2, d;
#pragma unroll
  for (int e = 0; e < 8; ++e) {
    float xe = xv[e], pe = pv[e];
    a.u[e]  = f2b(xe * mkv[e] + pe * (1.f - mkv[e]));
    b2.u[e] = f2b(xe * mvv[e] + pe * (1.f - mvv[e]));
    d.u[e]  = f2b(xe * mrv[e] + pe * (1.f - mrv[e]));
  }
  *(int4*)(ok + base)  = a.i4;
  *(int4*)(ov + base)  = b2.i4;
  *(int4*)(orr + base) = d.i4;
}

// ---------------- 256x256 BK=64 8-wave pipelined GEMM (R8, proven) ---------
// LDS layout per tile: [256 rows][64 bf16] row-major, 128 B/row, with XOR
// swizzle: physical 16B-slot = logical slot ^ (row & 7). Staged via
// global_load_lds (linear LDS dest) with the inverse permutation applied to
// the per-lane GLOBAL source address.

__device__ __forceinline__ void stageHalf(
    const unsigned short* __restrict__ g,  // matrix base + block-row base
    const unsigned short* l,               // LDS tile base (elements)
    int rh, int kt, int w, int rl, int koffel)
{
#pragma unroll
  for (int c = 0; c < 2; ++c) {
    int rows = rh * 128 + (2 * w + c) * 8;   // 8-row subtile base
    gl_lds16(g + (size_t)(rows + rl) * 1024 + kt * 64 + koffel,
             l + rows * 64);
  }
}

template<int Q>
__device__ __forceinline__ void quadMfma(f32x4 (&acc)[8][4],
    bf16x8 a00, bf16x8 a01, bf16x8 a10, bf16x8 a11, bf16x8 (&b)[4][2])
{
#pragma unroll
  for (int j = 0; j < 4; ++j) {
    acc[2*Q][j]   = __builtin_amdgcn_mfma_f32_16x16x32_bf16(a00, b[j][0], acc[2*Q][j],   0, 0, 0);
    acc[2*Q][j]   = __builtin_amdgcn_mfma_f32_16x16x32_bf16(a01, b[j][1], acc[2*Q][j],   0, 0, 0);
    acc[2*Q+1][j] = __builtin_amdgcn_mfma_f32_16x16x32_bf16(a10, b[j][0], acc[2*Q+1][j], 0, 0, 0);
    acc[2*Q+1][j] = __builtin_amdgcn_mfma_f32_16x16x32_bf16(a11, b[j][1], acc[2*Q+1][j], 0, 0, 0);
  }
}

// One K-tile = 4 phases / 8 barriers. Stage targets are always >=2 barriers
// past the last read of the buffer they overwrite (the load-bearing
// invariant - R9's 1-barrier variant raced). vmcnt(4) checkpoint once per
// K-tile leaves the 2 newest half-tiles (B(t+2)) in flight.
template<bool ST_A, bool ST_B, int VMN>
__device__ __forceinline__ void ktile(
    const unsigned short* aR, const unsigned short* bR,
    const unsigned short* aW, const unsigned short* bW,
    const unsigned short* Am, const unsigned short* Wn,
    int ktA, int ktB, int w, int wm, int wn, int col, int quad,
    int swzel, int rl, int koffel, f32x4 (&acc)[8][4])
{
  const int ks0 = (quad * 8) ^ swzel;        // k-slice 0 slot (elements)
  const int ks1 = (32 + quad * 8) ^ swzel;   // k-slice 1 slot
  // B fragments for the whole tile, kept in registers through all 4 phases
  bf16x8 b[4][2];
#pragma unroll
  for (int j = 0; j < 4; ++j) {
    const unsigned short* br = bR + (wn * 64 + j * 16 + col) * 64;
    b[j][0] = *(const bf16x8*)(br + ks0);
    b[j][1] = *(const bf16x8*)(br + ks1);
  }
  const unsigned short* ar = aR + (wm * 128 + col) * 64;
  // ---- Phase 1 (quadrant 0) ----
  {
    bf16x8 a00 = *(const bf16x8*)(ar + 0 * 1024 + ks0);
    bf16x8 a01 = *(const bf16x8*)(ar + 0 * 1024 + ks1);
    bf16x8 a10 = *(const bf16x8*)(ar + 1 * 1024 + ks0);
    bf16x8 a11 = *(const bf16x8*)(ar + 1 * 1024 + ks1);
    if (ST_A) stageHalf(Am, aW, 0, ktA, w, rl, koffel);
    SBAR(); LGKM0();
    __builtin_amdgcn_s_setprio(1);
    quadMfma<0>(acc, a00, a01, a10, a11, b);
    __builtin_amdgcn_s_setprio(0);
    SBAR();
  }
  // ---- Phase 2 (quadrant 1) ----
  {
    bf16x8 a00 = *(const bf16x8*)(ar + 2 * 1024 + ks0);
    bf16x8 a01 = *(const bf16x8*)(ar + 2 * 1024 + ks1);
    bf16x8 a10 = *(const bf16x8*)(ar + 3 * 1024 + ks0);
    bf16x8 a11 = *(const bf16x8*)(ar + 3 * 1024 + ks1);
    if (ST_A) stageHalf(Am, aW, 1, ktA, w, rl, koffel);
    SBAR(); LGKM0();
    __builtin_amdgcn_s_setprio(1);
    quadMfma<1>(acc, a00, a01, a10, a11, b);
    __builtin_amdgcn_s_setprio(0);
    SBAR();
  }
  // ---- Phase 3 (quadrant 2) ----
  {
    bf16x8 a00 = *(const bf16x8*)(ar + 4 * 1024 + ks0);
    bf16x8 a01 = *(const bf16x8*)(ar + 4 * 1024 + ks1);
    bf16x8 a10 = *(const bf16x8*)(ar + 5 * 1024 + ks0);
    bf16x8 a11 = *(const bf16x8*)(ar + 5 * 1024 + ks1);
    if (ST_B) stageHalf(Wn, bW, 0, ktB, w, rl, koffel);
    SBAR(); LGKM0();
    __builtin_amdgcn_s_setprio(1);
    quadMfma<2>(acc, a00, a01, a10, a11, b);
    __builtin_amdgcn_s_setprio(0);
    SBAR();
  }
  // ---- Phase 4 (quadrant 3) + vmcnt checkpoint ----
  {
    bf16x8 a00 = *(const bf16x8*)(ar + 6 * 1024 + ks0);
    bf16x8 a01 = *(const bf16x8*)(ar + 6 * 1024 + ks1);
    bf16x8 a10 = *(const bf16x8*)(ar + 7 * 1024 + ks0);
    bf16x8 a11 = *(const bf16x8*)(ar + 7 * 1024 + ks1);
    if (ST_B) stageHalf(Wn, bW, 1, ktB, w, rl, koffel);
    SBAR(); LGKM0();
    __builtin_amdgcn_s_setprio(1);
    quadMfma<3>(acc, a00, a01, a10, a11, b);
    __builtin_amdgcn_s_setprio(0);
    if constexpr (VMN == 4) { VMW(4); }
    else if constexpr (VMN == 0) { VMW(0); }
    SBAR();
  }
}

template<typename EPI>
__device__ __forceinline__ void gemm256(
    const unsigned short* __restrict__ A,
    const unsigned short* __restrict__ W,
    EPI epi)
{
  __shared__ __align__(16) unsigned short As[2][256 * 64];
  __shared__ __align__(16) unsigned short Bs[2][256 * 64];
  const int tid  = threadIdx.x;
  const int lane = tid & 63;
  const int w    = tid >> 6;          // wave 0..7
  const int wm   = w >> 2, wn = w & 3;
  const int col  = lane & 15, quad = lane >> 4;
  const int swzel  = (lane & 7) << 3;            // read-side XOR (elements)
  const int rl     = lane >> 3;                  // staging row-in-subtile
  const int koffel = ((lane & 7) ^ rl) << 3;     // pre-swizzled global k-off
  const int mBase = blockIdx.x * 256;
  const int nBase = blockIdx.y * 256;
  const unsigned short* Am = A + (size_t)mBase * 1024;
  const unsigned short* Wn = W + (size_t)nBase * 1024;

  f32x4 acc[8][4];
  const f32x4 z = {0.f, 0.f, 0.f, 0.f};
#pragma unroll
  for (int i = 0; i < 8; ++i)
#pragma unroll
    for (int j = 0; j < 4; ++j) acc[i][j] = z;

  // Prologue: B(0), A(0), B(1) = 12 loads/thread; drain oldest 8 (tile 0).
  stageHalf(Wn, &Bs[0][0], 0, 0, w, rl, koffel);
  stageHalf(Wn, &Bs[0][0], 1, 0, w, rl, koffel);
  stageHalf(Am, &As[0][0], 0, 0, w, rl, koffel);
  stageHalf(Am, &As[0][0], 1, 0, w, rl, koffel);
  stageHalf(Wn, &Bs[1][0], 0, 1, w, rl, koffel);
  stageHalf(Wn, &Bs[1][0], 1, 1, w, rl, koffel);
  VMW(4); SBAR();

#pragma unroll 1
  for (int t = 0; t < 14; t += 2) {
    ktile<true, true, 4>(&As[0][0], &Bs[0][0], &As[1][0], &Bs[0][0],
                         Am, Wn, t + 1, t + 2,
                         w, wm, wn, col, quad, swzel, rl, koffel, acc);
    ktile<true, true, 4>(&As[1][0], &Bs[1][0], &As[0][0], &Bs[1][0],
                         Am, Wn, t + 2, t + 3,
                         w, wm, wn, col, quad, swzel, rl, koffel, acc);
  }
  // t = 14: stage only A(15); drain everything (incl. B(15)) at checkpoint.
  ktile<true, false, 0>(&As[0][0], &Bs[0][0], &As[1][0], &Bs[0][0],
                        Am, Wn, 15, 0,
                        w, wm, wn, col, quad, swzel, rl, koffel, acc);
  // t = 15: pure compute.
  ktile<false, false, -1>(&As[1][0], &Bs[1][0], &As[0][0], &Bs[1][0],
                          Am, Wn, 0, 0,
                          w, wm, wn, col, quad, swzel, rl, koffel, acc);

  const int mB = mBase + wm * 128, nB = nBase + wn * 64;
#pragma unroll
  for (int i = 0; i < 8; ++i)
#pragma unroll
    for (int j = 0; j < 4; ++j)
#pragma unroll
      for (int r = 0; r < 4; ++r)
        epi(mB + i * 16 + quad * 4 + r, nB + j * 16 + col, acc[i][j][r]);
}

// fused K/V projection GEMM: z=0 -> kb, z=1 -> vb
__global__ __launch_bounds__(512, 2) void gemmKV2_kernel(
    const unsigned short* __restrict__ A0, const unsigned short* __restrict__ A1,
    const unsigned short* __restrict__ W0, const unsigned short* __restrict__ W1,
    unsigned short* __restrict__ out0, unsigned short* __restrict__ out1)
{
  const int z = blockIdx.z;
  const unsigned short* A = z ? A1 : A0;
  const unsigned short* W = z ? W1 : W0;
  unsigned short* out = z ? out1 : out0;
  gemm256(A, W, [&](int r, int c, float v) {
    out[(size_t)r * 1024 + c] = f2b(v);
  });
}

// R projection: sigmoid epilogue, bf16 out
__global__ __launch_bounds__(512, 2) void gemmR2_kernel(
    const unsigned short* __restrict__ A, const unsigned short* __restrict__ W,
    unsigned short* __restrict__ out)
{
  gemm256(A, W, [&](int r, int c, float v) {
    out[(size_t)r * 1024 + c] = f2b(1.0f / (1.0f + __expf(-v)));
  });
}

// final GEMM: f32 output
__global__ __launch_bounds__(512, 2) void gemmO2_kernel(
    const unsigned short* __restrict__ A, const unsigned short* __restrict__ W,
    float* __restrict__ out)
{
  gemm256(A, W, [&](int r, int c, float v) {
    out[(size_t)r * 1024 + c] = v;
  });
}

// ---------------- WKV chunked scan (NC=32 chunks of L=64) — R6 form ---------
__global__ __launch_bounds__(256) void wkv_pass1(
    const unsigned short* __restrict__ kb, const unsigned short* __restrict__ vb,
    const float* __restrict__ td,
    float* __restrict__ snum, float* __restrict__ sden, float* __restrict__ smx,
    int T, int C, int L)
{
  int g = blockIdx.x * 256 + threadIdx.x;
  int bc = g & 8191;
  int ch = g >> 13;
  int c = bc & 1023;
  float w = -__expf(td[c]);
  float num = 0.f, den = 0.f, mx = -1e38f;
  size_t base = ((size_t)(bc >> 10) * T + (size_t)ch * L) * C + c;
  for (int j0 = 0; j0 < L; j0 += 8) {
    float kq[8], vq[8];
#pragma unroll
    for (int j = 0; j < 8; ++j) {
      size_t a = base + (size_t)(j0 + j) * C;
      kq[j] = b2f(kb[a]);
      vq[j] = b2f(vb[a]);
    }
#pragma unroll
    for (int j = 0; j < 8; ++j) {
      float k = kq[j], v = vq[j];
      float mw = mx + w;
      float ms = fmaxf(mw, k);
      float s1 = __expf(mw - ms);
      float s2 = __expf(k - ms);
      num = s1 * num + s2 * v;
      den = s1 * den + s2;
      mx = ms;
    }
  }
  int idx = ch * 8192 + bc;
  snum[idx] = num; sden[idx] = den; smx[idx] = mx;
}

__global__ __launch_bounds__(64) void wkv_pass2(
    const float* __restrict__ snum, const float* __restrict__ sden,
    const float* __restrict__ smx, const float* __restrict__ td,
    float* __restrict__ inum, float* __restrict__ iden, float* __restrict__ imx,
    int L)
{
  int bc = blockIdx.x * 64 + threadIdx.x;
  int c = bc & 1023;
  float Wl = -__expf(td[c]) * (float)L;
  float num = 0.f, den = 0.f, mx = -1e38f;
#pragma unroll
  for (int ch = 0; ch < 32; ++ch) {
    int idx = ch * 8192 + bc;
    inum[idx] = num; iden[idx] = den; imx[idx] = mx;
    float sn = snum[idx], sd = sden[idx], sm = smx[idx];
    float mi = mx + Wl;
    float mo = fmaxf(mi, sm);
    float e1 = __expf(mi - mo);
    float e2 = __expf(sm - mo);
    num = e1 * num + e2 * sn;
    den = e1 * den + e2 * sd;
    mx = mo;
  }
}

__global__ __launch_bounds__(256) void wkv_pass3(
    const unsigned short* __restrict__ kb, const unsigned short* __restrict__ vb,
    const unsigned short* __restrict__ rsig,
    const float* __restrict__ td, const float* __restrict__ tf,
    const float* __restrict__ inum, const float* __restrict__ iden,
    const float* __restrict__ imx,
    unsigned short* __restrict__ rwkv, int T, int C, int L)
{
  int g = blockIdx.x * 256 + threadIdx.x;
  int bc = g & 8191;
  int ch = g >> 13;
  int c = bc & 1023;
  float w = -__expf(td[c]);
  float u = tf[c];
  int idx = ch * 8192 + bc;
  float num = inum[idx], den = iden[idx], mx = imx[idx];
  size_t base = ((size_t)(bc >> 10) * T + (size_t)ch * L) * C + c;
  for (int j0 = 0; j0 < L; j0 += 8) {
    float kq[8], vq[8], rq[8];
#pragma unroll
    for (int j = 0; j < 8; ++j) {
      size_t a = base + (size_t)(j0 + j) * C;
      kq[j] = b2f(kb[a]);
      vq[j] = b2f(vb[a]);
      rq[j] = b2f(rsig[a]);
    }
#pragma unroll
    for (int j = 0; j < 8; ++j) {
      float k = kq[j], v = vq[j];
      float ku = k + u;
      float mo = fmaxf(mx, ku);
      float e1 = __expf(mx - mo);
      float e2 = __expf(ku - mo);
      float o = (e1 * num + e2 * v) / (e1 * den + e2);
      rwkv[base + (size_t)(j0 + j) * C] = f2b(rq[j] * o);
      float mw = mx + w;
      float ms = fmaxf(mw, k);
      float s1 = __expf(mw - ms);
      float s2 = __expf(k - ms);
      num = s1 * num + s2 * v;
      den = s1 * den + s2;
      mx = ms;
    }
  }
}

extern "C" void kernel_launch(void* const* d_in, const int* in_sizes, int n_in,
                              void* d_out, int out_size, void* d_ws, size_t ws_size,
                              hipStream_t stream)
{
  const float* x  = (const float*)d_in[0];
  const float* wk = (const float*)d_in[1];
  const float* wv = (const float*)d_in[2];
  const float* wr = (const float*)d_in[3];
  const float* wo = (const float*)d_in[4];
  const float* td = (const float*)d_in[5];
  const float* tf = (const float*)d_in[6];
  const float* mk = (const float*)d_in[7];
  const float* mv = (const float*)d_in[8];
  const float* mr = (const float*)d_in[9];

  const int B = 8, T = 2048, C = 1024;
  const int M = B * T;      // 16384
  const int NC = 32, L = 64;
  const size_t MB = 1024 * 1024;

  char* ws = (char*)d_ws;
  unsigned short* bufK = (unsigned short*)(ws);              // 32 MiB
  unsigned short* bufV = (unsigned short*)(ws + 32 * MB);    // 32 MiB
  unsigned short* bufR = (unsigned short*)(ws + 64 * MB);    // 32 MiB
  unsigned short* kb   = (unsigned short*)(ws + 96 * MB);    // 32 MiB
  unsigned short* wkb  = (unsigned short*)(ws + 128 * MB);   // 2 MiB each
  unsigned short* wvb  = (unsigned short*)(ws + 130 * MB);
  unsigned short* wrb  = (unsigned short*)(ws + 132 * MB);
  unsigned short* wob  = (unsigned short*)(ws + 134 * MB);
  float* snum = (float*)(ws + 136 * MB);                     // 1 MiB each
  float* sden = (float*)(ws + 137 * MB);
  float* smx  = (float*)(ws + 138 * MB);
  float* inum = (float*)(ws + 139 * MB);
  float* iden = (float*)(ws + 140 * MB);
  float* imx  = (float*)(ws + 141 * MB);
  unsigned short* vb   = (unsigned short*)(ws + 142 * MB);   // 32 MiB
  // reuse (strictly after producer of the region is fully consumed):
  unsigned short* rsig = bufV;  // written by gemmR; bufV dead after gemmKV
  unsigned short* rwkv = bufR;  // written by pass3; bufR dead after gemmR

  dim3 gKV(M / 256, C / 256, 2);   // 64 x 4 x 2 = 512 blocks (2 clean rounds)
  dim3 gG(M / 256, C / 256);       // 64 x 4 = 256 blocks (1 round)
  int scanBlocks = (B * C * NC) / 256;  // 1024

  prep_kernel<<<12288, 256, 0, stream>>>(x, wk, wv, wr, wo, wkb, wvb, wrb, wob,
                                         mk, mv, mr, bufK, bufV, bufR);
  gemmKV2_kernel<<<gKV, 512, 0, stream>>>(bufK, bufV, wkb, wvb, kb, vb);
  gemmR2_kernel<<<gG, 512, 0, stream>>>(bufR, wrb, rsig);
  wkv_pass1<<<scanBlocks, 256, 0, stream>>>(kb, vb, td, snum, sden, smx, T, C, L);
  wkv_pass2<<<(B * C) / 64, 64, 0, stream>>>(snum, sden, smx, td, inum, iden, imx, L);
  wkv_pass3<<<scanBlocks, 256, 0, stream>>>(kb, vb, rsig, td, tf, inum, iden, imx,
                                            rwkv, T, C, L);
  gemmO2_kernel<<<gG, 512, 0, stream>>>(rwkv, wob, (float*)d_out);
}